// Round 4
// baseline (669.402 us; speedup 1.0000x reference)
//
#include <hip/hip_runtime.h>
#include <hip/hip_bf16.h>

// Problem constants (fixed by reference)
#define B_  64
#define S_  1024
#define D_  1024   // ATT_DIM  (GEMM N)
#define K_  1024   // ATTEND_DIM / QUERY_DIM (GEMM K)

typedef unsigned short u16;
typedef short bf16x8 __attribute__((ext_vector_type(8)));
typedef float f32x4  __attribute__((ext_vector_type(4)));
typedef u16   u16x8  __attribute__((ext_vector_type(8)));
typedef u16   u16x4  __attribute__((ext_vector_type(4)));

// ---------------- workspace layout (byte offsets) ----------------
// target  : 65536 f32          [0,       262144)   target[n*64+b]
// epart   : 65536*8 f32        [262144,  2359296)
// wcpart  : 64*16*1024 f32     [2359296, 6553600)
// wpre_bf : 1024*1024 u16      [6553600, 8650752)
// ctx_bf  : 64*1024*1024 u16   [8650752, 142868480)  (optional)
#define WS_TARGET 0
#define WS_EPART  262144
#define WS_WCPART 2359296
#define WS_WPRE   6553600
#define WS_CTXBF  8650752
#define WS_NEED_BF 142868480ull

__device__ __forceinline__ u16 f2bf(float f) {
    unsigned u = __float_as_uint(f);
    return (u16)((u + 0x7fffu + ((u >> 16) & 1u)) >> 16);
}
__device__ __forceinline__ float bf2f(u16 h) {
    return __uint_as_float(((unsigned)h) << 16);
}
__device__ __forceinline__ float fast_tanh(float x) {
    float t = __expf(2.0f * x);
    return 1.0f - 2.0f * __builtin_amdgcn_rcpf(t + 1.0f);
}

// direct global->LDS DMA, 16 B per lane; LDS dest = wave-uniform base + lane*16
__device__ __forceinline__ void glds16(const void* g, void* l) {
    __builtin_amdgcn_global_load_lds(
        (__attribute__((address_space(1))) void*)(size_t)g,
        (__attribute__((address_space(3))) void*)(unsigned int)(size_t)l,
        16, 0, 0);
}

// ---------------- fp32 -> bf16 conversion (8 elems/thread, 16B stores) ----------------
__global__ void convert_bf16x8_kernel(const float* __restrict__ src, u16* __restrict__ dst) {
    size_t i = ((size_t)blockIdx.x * 256 + threadIdx.x) * 8;
    float4 a = *reinterpret_cast<const float4*>(src + i);
    float4 b = *reinterpret_cast<const float4*>(src + i + 4);
    u16x8 h = { f2bf(a.x), f2bf(a.y), f2bf(a.z), f2bf(a.w),
                f2bf(b.x), f2bf(b.y), f2bf(b.z), f2bf(b.w) };
    *reinterpret_cast<u16x8*>(dst + i) = h;
}

// ---------------- target[n*64+b] = dot(input[b], Wq[n]) ----------------
// pair = n*64+b so consecutive blocks share the same Wq row (L1/L2 hit).
__global__ void target_kernel(const float* __restrict__ inp, const float* __restrict__ wq,
                              float* __restrict__ target) {
    int tid  = threadIdx.x;
    int lane = tid & 63, wid = tid >> 6;
    int pair = blockIdx.x * 4 + wid;          // pair = n*64 + b
    int b = pair & 63, n = pair >> 6;
    const float* ir = inp + (size_t)b * K_;
    const float* wr = wq  + (size_t)n * K_;
    float acc = 0.f;
#pragma unroll
    for (int jj = 0; jj < 4; ++jj) {
        int off = jj * 256 + lane * 4;
        float4 a = *reinterpret_cast<const float4*>(ir + off);
        float4 w = *reinterpret_cast<const float4*>(wr + off);
        acc += a.x * w.x + a.y * w.y + a.z * w.z + a.w * w.w;
    }
#pragma unroll
    for (int off = 1; off < 64; off <<= 1) acc += __shfl_xor(acc, off);
    if (lane == 0) target[pair] = acc;
}

// ===== fast GEMM: m97 geometry — 128x128 block, 4 waves, 64x64 wave tile =====
// Rationale (R3 post-mortem): previous 256x128 tile needed acc[8][4] = 128 AGPR
// + 92 VGPR ~ 220 unified regs -> 2 waves/SIMD (Occupancy 22%) -> MfmaUtil
// pinned at ~24% regardless of schedule (dbuf/T2/T4 all neutral). m97's
// verified 874-TF config uses a 64x64 wave tile (64 AGPR acc) at 3 waves/SIMD;
// wave-level TLP (m114) does the pipelining. Single-buffered LDS, plain
// 2-barrier loop, launch_bounds(256,3) pins the 3-waves/SIMD register class.
//
// LDS XOR swizzle kept (verified SQ_LDS_BANK_CONFLICT = 0):
//   16B-slot s_phys of row r holds logical slot s_phys ^ ((r>>1)&3); the
//   glds16 writer pre-swizzles the GLOBAL source chunk ((l&3)^((l>>3)&3));
//   reader slot = quad ^ ((lr>>1)&3) (per-thread constant).
__global__ __launch_bounds__(256, 3)
void gemm_ep_fast(const u16* __restrict__ ctxb, const u16* __restrict__ wpre,
                  const float* __restrict__ bpre, const float* __restrict__ wv,
                  const float* __restrict__ wcov, const float* __restrict__ target,
                  const float* __restrict__ cov, float* __restrict__ pre_out,
                  float* __restrict__ epart) {
    __shared__ __align__(16) u16 As[128 * 32];   // 8 KB
    __shared__ __align__(16) u16 Bs[128 * 32];   // 8 KB
    __shared__ float esm[128];

    const int tid  = threadIdx.x;
    const int lane = tid & 63;
    const int wid  = tid >> 6;                // 0..3
    const int wm = wid >> 1, wn = wid & 1;    // 2x2 wave grid over 128x128
    const int lr = lane & 15, quad = lane >> 4;
    const int sq = quad ^ ((lr >> 1) & 3);    // swizzled read slot (const/thread)

    // XCD-aware swizzle: each XCD owns mt = xcd (mod 8); nt varies fastest so
    // the 256 KB A-panel is reused across 8 consecutive blocks on one XCD's L2.
    // Bijective: 4096 blocks = 512 mt x 8 nt, 4096 % 8 == 0.
    const int lin  = blockIdx.x;              // 0..4095
    const int xcd  = lin & 7;
    const int slot = lin >> 3;                // 0..511
    const int mt   = (slot >> 3) * 8 + xcd;   // 0..511
    const int nt   = slot & 7;                // 0..7
    const int m_base = mt * 128;
    const int n_base = nt * 128;
    const int b      = m_base >> 10;          // 1024 % 128 == 0: no b straddle
    const int s_base = m_base & 1023;

    // staging: lane l -> row +l/4, SWIZZLED col chunk ((l&3)^((l>>3)&3))*8 shorts.
    // Per wave per K-tile: 2 A-chunks + 2 B-chunks (16 rows x 64 B each).
    const int srow = lane >> 2;
    const int scol = ((lane & 3) ^ ((lane >> 3) & 3)) * 8;
    const u16* gA = ctxb + (size_t)(m_base + wid * 32 + srow) * K_ + scol;
    const u16* gB = wpre + (size_t)(n_base + wid * 32 + srow) * K_ + scol;
    u16* lA = &As[(wid * 32) * 32];
    u16* lB = &Bs[(wid * 32) * 32];

    f32x4 acc[4][4];
#pragma unroll
    for (int i = 0; i < 4; ++i)
#pragma unroll
        for (int j = 0; j < 4; ++j) acc[i][j] = (f32x4){0.f, 0.f, 0.f, 0.f};

    if (tid < 128) esm[tid] = 0.0f;   // published by first K-loop barrier

    for (int kt = 0; kt < 32; ++kt) {
        const int k0 = kt * 32;
        glds16(gA + k0,                      lA);
        glds16(gA + (size_t)16 * K_ + k0,    lA + 16 * 32);
        glds16(gB + k0,                      lB);
        glds16(gB + (size_t)16 * K_ + k0,    lB + 16 * 32);
        __syncthreads();   // drains vmcnt (DMA landed) — m97 semantics

        bf16x8 af[4], bfr[4];
#pragma unroll
        for (int i = 0; i < 4; ++i)
            af[i] = *reinterpret_cast<const bf16x8*>(
                &As[(wm * 64 + i * 16 + lr) * 32 + sq * 8]);
#pragma unroll
        for (int j = 0; j < 4; ++j)
            bfr[j] = *reinterpret_cast<const bf16x8*>(
                &Bs[(wn * 64 + j * 16 + lr) * 32 + sq * 8]);
#pragma unroll
        for (int i = 0; i < 4; ++i)
#pragma unroll
            for (int j = 0; j < 4; ++j)
                acc[i][j] = __builtin_amdgcn_mfma_f32_16x16x32_bf16(
                    af[i], bfr[j], acc[i][j], 0, 0, 0);
        __syncthreads();   // reads done before next stage overwrites
    }

    // ---- epilogue: +b_pre, store precompute (non-temporal), tanh, energy partial ----
    float bpre_j[4], wv_j[4], wcov_j[4], tgt_j[4];
    int n_j[4];
#pragma unroll
    for (int j = 0; j < 4; ++j) {
        n_j[j]    = n_base + wn * 64 + j * 16 + lr;
        bpre_j[j] = bpre[n_j[j]];
        wv_j[j]   = wv[n_j[j]];
        wcov_j[j] = wcov[n_j[j]];
        tgt_j[j]  = target[n_j[j] * 64 + b];
    }
#pragma unroll
    for (int i = 0; i < 4; ++i) {
#pragma unroll
        for (int r = 0; r < 4; ++r) {
            int row_local = wm * 64 + i * 16 + quad * 4 + r;   // 0..127
            int m = m_base + row_local;
            int s = s_base + row_local;
            float c = cov[b * S_ + s];
            float esum = 0.f;
#pragma unroll
            for (int j = 0; j < 4; ++j) {
                float pre = acc[i][j][r] + bpre_j[j];
                __builtin_nontemporal_store(pre, &pre_out[(size_t)m * D_ + n_j[j]]);
                float t = fast_tanh(pre + tgt_j[j] + c * wcov_j[j]);
                esum += t * wv_j[j];
            }
            esum += __shfl_xor(esum, 1);
            esum += __shfl_xor(esum, 2);
            esum += __shfl_xor(esum, 4);
            esum += __shfl_xor(esum, 8);
            if (lr == 0) atomicAdd(&esm[row_local], esum);
        }
    }
    __syncthreads();
    if (tid < 128) epart[(size_t)(m_base + tid) * 8 + nt] = esm[tid];
}

// ================= fallback GEMM (fp32 inputs, manual staging) =================
#define LDA 40
__global__ __launch_bounds__(256, 2)
void gemm_ep_fallback(const float* __restrict__ ctxf, const u16* __restrict__ wpre,
                      const float* __restrict__ bpre, const float* __restrict__ wv,
                      const float* __restrict__ wcov, const float* __restrict__ target,
                      const float* __restrict__ cov, float* __restrict__ pre_out,
                      float* __restrict__ epart) {
    __shared__ __align__(16) u16 As[256 * LDA];
    __shared__ __align__(16) u16 Bs[128 * LDA];
    __shared__ float esm[256];
    const int tid  = threadIdx.x;
    const int lane = tid & 63;
    const int wid  = tid >> 6;
    const int wm = wid >> 1, wn = wid & 1;
    const int lr = lane & 15, quad = lane >> 4;
    const int m_base = blockIdx.y * 256;
    const int n_base = blockIdx.x * 128;
    const int b      = m_base >> 10;
    const int s_base = m_base & 1023;

    f32x4 acc[8][4];
#pragma unroll
    for (int i = 0; i < 8; ++i)
#pragma unroll
        for (int j = 0; j < 4; ++j) acc[i][j] = (f32x4){0.f, 0.f, 0.f, 0.f};
    esm[tid] = 0.0f;

    for (int kt = 0; kt < 32; ++kt) {
        const int k0 = kt * 32;
        {
            const int row0 = tid >> 3, kc = (tid & 7) * 4;
#pragma unroll
            for (int p = 0; p < 8; ++p) {
                int row = row0 + p * 32;
                float4 v = *reinterpret_cast<const float4*>(
                    ctxf + (size_t)(m_base + row) * K_ + k0 + kc);
                u16x4 h = { f2bf(v.x), f2bf(v.y), f2bf(v.z), f2bf(v.w) };
                *reinterpret_cast<u16x4*>(&As[row * LDA + kc]) = h;
            }
        }
        {
            const int row0 = tid >> 2, kc = (tid & 3) * 8;
#pragma unroll
            for (int p = 0; p < 2; ++p) {
                int row = row0 + p * 64;
                u16x8 v = *reinterpret_cast<const u16x8*>(
                    wpre + (size_t)(n_base + row) * K_ + k0 + kc);
                *reinterpret_cast<u16x8*>(&Bs[row * LDA + kc]) = v;
            }
        }
        __syncthreads();
        bf16x8 af[8], bfr[4];
#pragma unroll
        for (int i = 0; i < 8; ++i)
            af[i] = *reinterpret_cast<const bf16x8*>(&As[(wm * 128 + i * 16 + lr) * LDA + quad * 8]);
#pragma unroll
        for (int j = 0; j < 4; ++j)
            bfr[j] = *reinterpret_cast<const bf16x8*>(&Bs[(wn * 64 + j * 16 + lr) * LDA + quad * 8]);
#pragma unroll
        for (int i = 0; i < 8; ++i)
#pragma unroll
            for (int j = 0; j < 4; ++j)
                acc[i][j] = __builtin_amdgcn_mfma_f32_16x16x32_bf16(af[i], bfr[j], acc[i][j], 0, 0, 0);
        __syncthreads();
    }
    float bpre_j[4], wv_j[4], wcov_j[4], tgt_j[4];
    int n_j[4];
#pragma unroll
    for (int j = 0; j < 4; ++j) {
        n_j[j]    = n_base + wn * 64 + j * 16 + lr;
        bpre_j[j] = bpre[n_j[j]];
        wv_j[j]   = wv[n_j[j]];
        wcov_j[j] = wcov[n_j[j]];
        tgt_j[j]  = target[n_j[j] * 64 + b];
    }
#pragma unroll
    for (int i = 0; i < 8; ++i) {
#pragma unroll
        for (int r = 0; r < 4; ++r) {
            int row_local = wm * 128 + i * 16 + quad * 4 + r;
            int m = m_base + row_local;
            int s = s_base + row_local;
            float c = cov[b * S_ + s];
            float esum = 0.f;
#pragma unroll
            for (int j = 0; j < 4; ++j) {
                float pre = acc[i][j][r] + bpre_j[j];
                __builtin_nontemporal_store(pre, &pre_out[(size_t)m * D_ + n_j[j]]);
                float t = fast_tanh(pre + tgt_j[j] + c * wcov_j[j]);
                esum += t * wv_j[j];
            }
            esum += __shfl_xor(esum, 1);
            esum += __shfl_xor(esum, 2);
            esum += __shfl_xor(esum, 4);
            esum += __shfl_xor(esum, 8);
            if (lr == 0) atomicAdd(&esm[row_local], esum);
        }
    }
    __syncthreads();
    epart[(size_t)(m_base + tid) * 8 + blockIdx.x] = esm[tid];
}

// ---------------- softmax over S + coverage_new ----------------
__global__ void softmax_cov_kernel(const float* __restrict__ epart, const float* __restrict__ cov,
                                   float* __restrict__ score, float* __restrict__ covnew) {
    int b = blockIdx.x, t = threadIdx.x;
    int lane = t & 63, wid = t >> 6;
    __shared__ float red[4];
    float e[4];
    float lmax = -3.4e38f;
#pragma unroll
    for (int p = 0; p < 4; ++p) {
        int s = p * 256 + t;
        const float4* q = reinterpret_cast<const float4*>(epart + (size_t)(b * S_ + s) * 8);
        float4 a = q[0], c = q[1];
        e[p] = a.x + a.y + a.z + a.w + c.x + c.y + c.z + c.w;
        lmax = fmaxf(lmax, e[p]);
    }
#pragma unroll
    for (int off = 1; off < 64; off <<= 1) lmax = fmaxf(lmax, __shfl_xor(lmax, off));
    if (lane == 0) red[wid] = lmax;
    __syncthreads();
    float bm = fmaxf(fmaxf(red[0], red[1]), fmaxf(red[2], red[3]));
    __syncthreads();
    float ex[4];
    float lsum = 0.f;
#pragma unroll
    for (int p = 0; p < 4; ++p) { ex[p] = __expf(e[p] - bm); lsum += ex[p]; }
#pragma unroll
    for (int off = 1; off < 64; off <<= 1) lsum += __shfl_xor(lsum, off);
    if (lane == 0) red[wid] = lsum;
    __syncthreads();
    float total = red[0] + red[1] + red[2] + red[3];
    float inv = __builtin_amdgcn_rcpf(total);
#pragma unroll
    for (int p = 0; p < 4; ++p) {
        int s = p * 256 + t;
        float sc = ex[p] * inv;
        score[b * S_ + s]  = sc;
        covnew[b * S_ + s] = cov[b * S_ + s] + sc;
    }
}

// ---------------- weightedContext = score @ context ----------------
__global__ void wc_partial_bf(const float* __restrict__ score, const u16* __restrict__ ctxb,
                              float* __restrict__ part) {
    int sp = blockIdx.x, b = blockIdx.y, t = threadIdx.x;   // sp in [0,16)
    int col = t * 4;
    float ax = 0.f, ay = 0.f, az = 0.f, aw = 0.f;
    const u16*   base  = ctxb + ((size_t)b * S_ + sp * 64) * K_ + col;
    const float* sbase = score + b * S_ + sp * 64;
    for (int ss = 0; ss < 64; ++ss) {
        float w = sbase[ss];
        u16x4 c = *reinterpret_cast<const u16x4*>(base + (size_t)ss * K_);
        ax += w * bf2f(c[0]); ay += w * bf2f(c[1]);
        az += w * bf2f(c[2]); aw += w * bf2f(c[3]);
    }
    float4 o = { ax, ay, az, aw };
    *reinterpret_cast<float4*>(part + (size_t)(b * 16 + sp) * 1024 + col) = o;
}

__global__ void wc_partial_f32(const float* __restrict__ score, const float* __restrict__ ctx,
                               float* __restrict__ part) {
    int sp = blockIdx.x, b = blockIdx.y, t = threadIdx.x;
    int col = t * 4;
    float ax = 0.f, ay = 0.f, az = 0.f, aw = 0.f;
    const float* base  = ctx + ((size_t)b * S_ + sp * 64) * K_ + col;
    const float* sbase = score + b * S_ + sp * 64;
    for (int ss = 0; ss < 64; ++ss) {
        float w = sbase[ss];
        float4 c = *reinterpret_cast<const float4*>(base + (size_t)ss * K_);
        ax += w * c.x; ay += w * c.y; az += w * c.z; aw += w * c.w;
    }
    float4 o = { ax, ay, az, aw };
    *reinterpret_cast<float4*>(part + (size_t)(b * 16 + sp) * 1024 + col) = o;
}

__global__ void wc_reduce_kernel(const float* __restrict__ part, float* __restrict__ wc) {
    int b = blockIdx.x, t = threadIdx.x;
    int col = t * 4;
    float ax = 0.f, ay = 0.f, az = 0.f, aw = 0.f;
#pragma unroll
    for (int p = 0; p < 16; ++p) {
        float4 v = *reinterpret_cast<const float4*>(part + (size_t)(b * 16 + p) * 1024 + col);
        ax += v.x; ay += v.y; az += v.z; aw += v.w;
    }
    float4 o = { ax, ay, az, aw };
    *reinterpret_cast<float4*>(wc + b * 1024 + col) = o;
}

// ---------------- host ----------------
extern "C" void kernel_launch(void* const* d_in, const int* in_sizes, int n_in,
                              void* d_out, int out_size, void* d_ws, size_t ws_size,
                              hipStream_t stream) {
    const float* input = (const float*)d_in[0];
    const float* ctx   = (const float*)d_in[1];
    const float* cov   = (const float*)d_in[2];
    const float* Wpre  = (const float*)d_in[3];
    const float* bpre  = (const float*)d_in[4];
    const float* Wq    = (const float*)d_in[5];
    const float* Wv    = (const float*)d_in[6];
    const float* Wcov  = (const float*)d_in[7];

    float* out        = (float*)d_out;
    float* out_wc     = out;                 // (B, 1024)
    float* out_score  = out + 65536;         // (B, S)
    float* out_covnew = out + 131072;        // (B, S)
    float* out_pre    = out + 196608;        // (B, S, D)

    char*  ws        = (char*)d_ws;
    float* ws_target = (float*)(ws + WS_TARGET);
    float* ws_epart  = (float*)(ws + WS_EPART);
    float* ws_wcpart = (float*)(ws + WS_WCPART);
    u16*   ws_wpre   = (u16*)(ws + WS_WPRE);
    u16*   ws_ctxbf  = (u16*)(ws + WS_CTXBF);

    const bool use_bf = (ws_size >= WS_NEED_BF);

    // 1. W_pre -> bf16 (1M elems, 8/thread)
    convert_bf16x8_kernel<<<512, 256, 0, stream>>>(Wpre, ws_wpre);
    // 2. context -> bf16 (67.1M elems)
    if (use_bf)
        convert_bf16x8_kernel<<<32768, 256, 0, stream>>>(ctx, ws_ctxbf);
    // 3. target = input @ W_q^T  (stored target[n*64+b])
    target_kernel<<<16384, 256, 0, stream>>>(input, Wq, ws_target);
    // 4. GEMM + fused tanh/energy epilogue (128x128 tiles: 512 mt x 8 nt)
    if (use_bf)
        gemm_ep_fast<<<4096, 256, 0, stream>>>(ws_ctxbf, ws_wpre, bpre, Wv, Wcov,
                                               ws_target, cov, out_pre, ws_epart);
    else {
        dim3 ggrid(8, 256);
        gemm_ep_fallback<<<ggrid, 256, 0, stream>>>(ctx, ws_wpre, bpre, Wv, Wcov,
                                                    ws_target, cov, out_pre, ws_epart);
    }
    // 5. softmax + coverage_new
    softmax_cov_kernel<<<64, 256, 0, stream>>>(ws_epart, cov, out_score, out_covnew);
    // 6. weightedContext
    if (use_bf)
        wc_partial_bf<<<dim3(16, 64), 256, 0, stream>>>(out_score, ws_ctxbf, ws_wcpart);
    else
        wc_partial_f32<<<dim3(16, 64), 256, 0, stream>>>(out_score, ctx, ws_wcpart);
    wc_reduce_kernel<<<64, 256, 0, stream>>>(ws_wcpart, out_wc);
}

// Round 5
// 641.136 us; speedup vs baseline: 1.0441x; 1.0441x over previous
//
#include <hip/hip_runtime.h>
#include <hip/hip_bf16.h>

// Problem constants (fixed by reference)
#define B_  64
#define S_  1024
#define D_  1024   // ATT_DIM  (GEMM N)
#define K_  1024   // ATTEND_DIM / QUERY_DIM (GEMM K)

typedef unsigned short u16;
typedef short bf16x8 __attribute__((ext_vector_type(8)));
typedef float f32x4  __attribute__((ext_vector_type(4)));
typedef u16   u16x8  __attribute__((ext_vector_type(8)));
typedef u16   u16x4  __attribute__((ext_vector_type(4)));

// ---------------- workspace layout (byte offsets) ----------------
#define WS_TARGET 0
#define WS_EPART  262144
#define WS_WCPART 2359296
#define WS_WPRE   6553600
#define WS_CTXBF  8650752
#define WS_NEED_BF 142868480ull

__device__ __forceinline__ u16 f2bf(float f) {
    unsigned u = __float_as_uint(f);
    return (u16)((u + 0x7fffu + ((u >> 16) & 1u)) >> 16);
}
__device__ __forceinline__ float bf2f(u16 h) {
    return __uint_as_float(((unsigned)h) << 16);
}
__device__ __forceinline__ float fast_tanh(float x) {
    float t = __expf(2.0f * x);
    return 1.0f - 2.0f * __builtin_amdgcn_rcpf(t + 1.0f);
}

// direct global->LDS DMA, 16 B per lane; LDS dest = wave-uniform base + lane*16
__device__ __forceinline__ void glds16(const void* g, void* l) {
    __builtin_amdgcn_global_load_lds(
        (__attribute__((address_space(1))) void*)(size_t)g,
        (__attribute__((address_space(3))) void*)(unsigned int)(size_t)l,
        16, 0, 0);
}

// ---------------- fp32 -> bf16 conversion ----------------
__global__ void convert_bf16x8_kernel(const float* __restrict__ src, u16* __restrict__ dst) {
    size_t i = ((size_t)blockIdx.x * 256 + threadIdx.x) * 8;
    float4 a = *reinterpret_cast<const float4*>(src + i);
    float4 b = *reinterpret_cast<const float4*>(src + i + 4);
    u16x8 h = { f2bf(a.x), f2bf(a.y), f2bf(a.z), f2bf(a.w),
                f2bf(b.x), f2bf(b.y), f2bf(b.z), f2bf(b.w) };
    *reinterpret_cast<u16x8*>(dst + i) = h;
}

// ---------------- target[n*64+b] = dot(input[b], Wq[n]) ----------------
__global__ void target_kernel(const float* __restrict__ inp, const float* __restrict__ wq,
                              float* __restrict__ target) {
    int tid  = threadIdx.x;
    int lane = tid & 63, wid = tid >> 6;
    int pair = blockIdx.x * 4 + wid;          // pair = n*64 + b
    int b = pair & 63, n = pair >> 6;
    const float* ir = inp + (size_t)b * K_;
    const float* wr = wq  + (size_t)n * K_;
    float acc = 0.f;
#pragma unroll
    for (int jj = 0; jj < 4; ++jj) {
        int off = jj * 256 + lane * 4;
        float4 a = *reinterpret_cast<const float4*>(ir + off);
        float4 w = *reinterpret_cast<const float4*>(wr + off);
        acc += a.x * w.x + a.y * w.y + a.z * w.z + a.w * w.w;
    }
#pragma unroll
    for (int off = 1; off < 64; off <<= 1) acc += __shfl_xor(acc, off);
    if (lane == 0) target[pair] = acc;
}

// ===================== 8-phase 256x256 GEMM (T2+T3+T4+T5) =====================
// 512 threads = 8 waves (2M x 4N); wave tile 128x64 = acc[8][4]; BK=64, 16 K-tiles,
// 8 iterations x 8 phases (2 tiles/iter). LDS: A0/A1/B0/B1 [256][64] bf16 = 128 KB.
//
// Phase p (uniform): { 4-8 ds_read_b128  |  stage 1 half-tile (2 glds16) }
//   -> s_barrier -> lgkmcnt(0)+sched_barrier (rule #18) -> setprio(1) -> 16 MFMA
//   -> setprio(0) -> [vmcnt(2) at p3/p7 only] -> s_barrier -> sched_barrier.
//
// Staging map (tile t lives in buf t&1; all windows verified vs read phases):
//   p0: A1-low<-t(2i+1)   p1: A1-high<-t(2i+1)   p2: B1-high<-t(2i+1)
//   p3: B0-low<-t(2i+2)   p4: A0-low<-t(2i+2)    p5: A0-high<-t(2i+2)
//   p6: B0-high<-t(2i+2)  p7: B1-low<-t(2i+3)
//   (B1-low of tile 2i+1 was staged at previous iteration's p7.)
// vmcnt(2) at p3/p7 = everything except the just-issued half-tile has landed ->
// the current tile is complete for ALL waves after the following barrier, while
// one half-tile stays in flight across the boundary (T4: never drain to 0).
//
// LDS swizzle (T2, glds16-compatible per rule #21): row stride 128 B = 8 x 16B
// slots; phys slot = logical ^ (row&7). Writer: glds16 is linear (lane -> row
// lane>>3, slot lane&7), so the GLOBAL source chunk is pre-swizzled:
// ((lane&7)^(lane>>3))*8 shorts. Reader: slot = (h*4+quad) ^ (lr&7).
__global__ __launch_bounds__(512, 2)
void gemm_ep_fast(const u16* __restrict__ ctxb, const u16* __restrict__ wpre,
                  const float* __restrict__ bpre, const float* __restrict__ wv,
                  const float* __restrict__ wcov, const float* __restrict__ target,
                  const float* __restrict__ cov, float* __restrict__ pre_out,
                  float* __restrict__ epart) {
    __shared__ __align__(16) u16 A0[256 * 64];   // 32 KB each
    __shared__ __align__(16) u16 A1[256 * 64];
    __shared__ __align__(16) u16 B0[256 * 64];
    __shared__ __align__(16) u16 B1[256 * 64];
    __shared__ float esm[256];

    const int tid  = threadIdx.x;
    const int lane = tid & 63;
    const int wid  = tid >> 6;                 // 0..7
    const int wm = wid >> 2, wn = wid & 3;     // 2 x 4 wave grid
    const int lr = lane & 15, quad = lane >> 4;

    // XCD swizzle: 1024 blocks = 32 mtg x 8 xcd x 4 nt (bijective, 1024%8==0)
    const int lin  = blockIdx.x;
    const int xcd  = lin & 7;
    const int slot = lin >> 3;                 // 0..127
    const int nt   = slot & 3;                 // 0..3
    const int mt   = (slot >> 2) * 8 + xcd;    // 0..255
    const int m_base = mt * 256;
    const int n_base = nt * 256;
    const int b      = m_base >> 10;
    const int s_base = m_base & 1023;

    // staging source: lane l -> row +(l>>3), pre-swizzled chunk ((l&7)^(l>>3))*8
    const int srow8 = lane >> 3;
    const int scol  = ((lane & 7) ^ (lane >> 3)) * 8;
    const u16* gA = ctxb + (size_t)(m_base + wid * 16 + srow8) * K_ + scol;
    const u16* gB = wpre + (size_t)(n_base + wid * 16 + srow8) * K_ + scol;

    f32x4 acc[8][4];
#pragma unroll
    for (int i = 0; i < 8; ++i)
#pragma unroll
        for (int j = 0; j < 4; ++j) acc[i][j] = (f32x4){0.f, 0.f, 0.f, 0.f};

// stage one half-tile (128 rows, this wave's 16 rows) of tile kt_ into larr
#define STG(garr, R, kt_, larr) do {                                           \
    glds16(garr + (size_t)(R) * K_ + (kt_) * 64,                               \
           &larr[((R) + wid * 16 + 0) * 64]);                                  \
    glds16(garr + (size_t)((R) + 8) * K_ + (kt_) * 64,                         \
           &larr[((R) + wid * 16 + 8) * 64]);                                  \
} while (0)

// A fragments: rows wm*128 + (ibase+ii)*16 + lr, k-half h, swizzled slot
#define LDA4(dst, arr, ibase, h)                                               \
    _Pragma("unroll") for (int ii = 0; ii < 4; ++ii)                           \
        dst[ii] = *reinterpret_cast<const bf16x8*>(                            \
            &arr[(wm * 128 + ((ibase) + ii) * 16 + lr) * 64 +                  \
                 ((((h) * 4 + quad) ^ (lr & 7)) * 8)]);
// B fragments: rows wn*64 + jj*16 + lr
#define LDB4(dst, arr, h)                                                      \
    _Pragma("unroll") for (int jj = 0; jj < 4; ++jj)                           \
        dst[jj] = *reinterpret_cast<const bf16x8*>(                            \
            &arr[(wn * 64 + jj * 16 + lr) * 64 +                               \
                 ((((h) * 4 + quad) ^ (lr & 7)) * 8)]);
#define MFMA16(ibase, A4, B4)                                                  \
    _Pragma("unroll") for (int ii = 0; ii < 4; ++ii)                           \
        _Pragma("unroll") for (int jj = 0; jj < 4; ++jj)                       \
            acc[(ibase) + ii][jj] = __builtin_amdgcn_mfma_f32_16x16x32_bf16(   \
                A4[ii], B4[jj], acc[(ibase) + ii][jj], 0, 0, 0);

#define PH_MID() do {                                                          \
    __builtin_amdgcn_s_barrier();                                              \
    asm volatile("s_waitcnt lgkmcnt(0)" ::: "memory");                         \
    __builtin_amdgcn_sched_barrier(0);                                         \
    __builtin_amdgcn_s_setprio(1);                                             \
} while (0)
#define PH_END() do {                                                          \
    __builtin_amdgcn_s_setprio(0);                                             \
    __builtin_amdgcn_s_barrier();                                              \
    __builtin_amdgcn_sched_barrier(0);                                         \
} while (0)
#define PH_END_VM() do {                                                       \
    __builtin_amdgcn_s_setprio(0);                                             \
    asm volatile("s_waitcnt vmcnt(2)" ::: "memory");                           \
    __builtin_amdgcn_s_barrier();                                              \
    __builtin_amdgcn_sched_barrier(0);                                         \
} while (0)

    bf16x8 alo[4], ahi[4], bfv[4];

    // prologue: tile 0 fully + tile 1 B-low; wait tile0 (2 newest stay in flight)
    STG(gA, 0, 0, A0); STG(gA, 128, 0, A0);
    STG(gB, 0, 0, B0); STG(gB, 128, 0, B0);
    STG(gB, 0, 1, B1);
    if (tid < 256) esm[tid] = 0.0f;
    asm volatile("s_waitcnt vmcnt(2)" ::: "memory");
    __builtin_amdgcn_s_barrier();
    __builtin_amdgcn_sched_barrier(0);

    for (int i = 0; i < 8; ++i) {
        const int t1 = 2 * i + 1;
        const int t2 = (2 * i + 2 < 16) ? 2 * i + 2 : 15;   // clamped (last iter)
        const int t3 = (2 * i + 3 < 16) ? 2 * i + 3 : 15;
        // p0
        LDA4(alo, A0, 0, 0); LDB4(bfv, B0, 0);
        STG(gA, 0, t1, A1);
        PH_MID(); MFMA16(0, alo, bfv); PH_END();
        // p1
        LDA4(ahi, A0, 4, 0);
        STG(gA, 128, t1, A1);
        PH_MID(); MFMA16(4, ahi, bfv); PH_END();
        // p2
        LDA4(alo, A0, 0, 1); LDB4(bfv, B0, 1);
        STG(gB, 128, t1, B1);
        PH_MID(); MFMA16(0, alo, bfv); PH_END();
        // p3  (tile boundary: tile t1 complete after this barrier)
        LDA4(ahi, A0, 4, 1);
        STG(gB, 0, t2, B0);
        PH_MID(); MFMA16(4, ahi, bfv); PH_END_VM();
        // p4
        LDA4(alo, A1, 0, 0); LDB4(bfv, B1, 0);
        STG(gA, 0, t2, A0);
        PH_MID(); MFMA16(0, alo, bfv); PH_END();
        // p5
        LDA4(ahi, A1, 4, 0);
        STG(gA, 128, t2, A0);
        PH_MID(); MFMA16(4, ahi, bfv); PH_END();
        // p6
        LDA4(alo, A1, 0, 1); LDB4(bfv, B1, 1);
        STG(gB, 128, t2, B0);
        PH_MID(); MFMA16(0, alo, bfv); PH_END();
        // p7  (tile boundary)
        LDA4(ahi, A1, 4, 1);
        STG(gB, 0, t3, B1);
        PH_MID(); MFMA16(4, ahi, bfv); PH_END_VM();
    }
    // drain: no in-flight DMA may outlive this block's LDS allocation
    asm volatile("s_waitcnt vmcnt(0)" ::: "memory");
#undef STG
#undef LDA4
#undef LDB4
#undef MFMA16
#undef PH_MID
#undef PH_END
#undef PH_END_VM

    // ---- epilogue: +b_pre, store precompute, tanh, energy partial ----
    float bpre_j[4], wv_j[4], wcov_j[4], tgt_j[4];
    int n_j[4];
#pragma unroll
    for (int j = 0; j < 4; ++j) {
        n_j[j]    = n_base + wn * 64 + j * 16 + lr;
        bpre_j[j] = bpre[n_j[j]];
        wv_j[j]   = wv[n_j[j]];
        wcov_j[j] = wcov[n_j[j]];
        tgt_j[j]  = target[n_j[j] * 64 + b];
    }
#pragma unroll
    for (int i = 0; i < 8; ++i) {
#pragma unroll
        for (int r = 0; r < 4; ++r) {
            int row_local = wm * 128 + i * 16 + quad * 4 + r;   // 0..255
            int m = m_base + row_local;
            int s = s_base + row_local;
            float c = cov[b * S_ + s];
            float esum = 0.f;
#pragma unroll
            for (int j = 0; j < 4; ++j) {
                float pre = acc[i][j][r] + bpre_j[j];
                __builtin_nontemporal_store(pre, &pre_out[(size_t)m * D_ + n_j[j]]);
                float t = fast_tanh(pre + tgt_j[j] + c * wcov_j[j]);
                esum += t * wv_j[j];
            }
            esum += __shfl_xor(esum, 1);
            esum += __shfl_xor(esum, 2);
            esum += __shfl_xor(esum, 4);
            esum += __shfl_xor(esum, 8);
            if (lr == 0) atomicAdd(&esm[row_local], esum);
        }
    }
    __syncthreads();
    if (tid < 256) {
        epart[(size_t)(m_base + tid) * 8 + nt]     = esm[tid];
        epart[(size_t)(m_base + tid) * 8 + nt + 4] = 0.0f;   // softmax sums 8 slots
    }
}

// ================= fallback GEMM (fp32 inputs, manual staging) =================
#define LDA 40
__global__ __launch_bounds__(256, 2)
void gemm_ep_fallback(const float* __restrict__ ctxf, const u16* __restrict__ wpre,
                      const float* __restrict__ bpre, const float* __restrict__ wv,
                      const float* __restrict__ wcov, const float* __restrict__ target,
                      const float* __restrict__ cov, float* __restrict__ pre_out,
                      float* __restrict__ epart) {
    __shared__ __align__(16) u16 As[256 * LDA];
    __shared__ __align__(16) u16 Bs[128 * LDA];
    __shared__ float esm[256];
    const int tid  = threadIdx.x;
    const int lane = tid & 63;
    const int wid  = tid >> 6;
    const int wm = wid >> 1, wn = wid & 1;
    const int lr = lane & 15, quad = lane >> 4;
    const int m_base = blockIdx.y * 256;
    const int n_base = blockIdx.x * 128;
    const int b      = m_base >> 10;
    const int s_base = m_base & 1023;

    f32x4 acc[8][4];
#pragma unroll
    for (int i = 0; i < 8; ++i)
#pragma unroll
        for (int j = 0; j < 4; ++j) acc[i][j] = (f32x4){0.f, 0.f, 0.f, 0.f};
    esm[tid] = 0.0f;

    for (int kt = 0; kt < 32; ++kt) {
        const int k0 = kt * 32;
        {
            const int row0 = tid >> 3, kc = (tid & 7) * 4;
#pragma unroll
            for (int p = 0; p < 8; ++p) {
                int row = row0 + p * 32;
                float4 v = *reinterpret_cast<const float4*>(
                    ctxf + (size_t)(m_base + row) * K_ + k0 + kc);
                u16x4 h = { f2bf(v.x), f2bf(v.y), f2bf(v.z), f2bf(v.w) };
                *reinterpret_cast<u16x4*>(&As[row * LDA + kc]) = h;
            }
        }
        {
            const int row0 = tid >> 2, kc = (tid & 3) * 8;
#pragma unroll
            for (int p = 0; p < 2; ++p) {
                int row = row0 + p * 64;
                u16x8 v = *reinterpret_cast<const u16x8*>(
                    wpre + (size_t)(n_base + row) * K_ + k0 + kc);
                *reinterpret_cast<u16x8*>(&Bs[row * LDA + kc]) = v;
            }
        }
        __syncthreads();
        bf16x8 af[8], bfr[4];
#pragma unroll
        for (int i = 0; i < 8; ++i)
            af[i] = *reinterpret_cast<const bf16x8*>(&As[(wm * 128 + i * 16 + lr) * LDA + quad * 8]);
#pragma unroll
        for (int j = 0; j < 4; ++j)
            bfr[j] = *reinterpret_cast<const bf16x8*>(&Bs[(wn * 64 + j * 16 + lr) * LDA + quad * 8]);
#pragma unroll
        for (int i = 0; i < 8; ++i)
#pragma unroll
            for (int j = 0; j < 4; ++j)
                acc[i][j] = __builtin_amdgcn_mfma_f32_16x16x32_bf16(af[i], bfr[j], acc[i][j], 0, 0, 0);
        __syncthreads();
    }
    float bpre_j[4], wv_j[4], wcov_j[4], tgt_j[4];
    int n_j[4];
#pragma unroll
    for (int j = 0; j < 4; ++j) {
        n_j[j]    = n_base + wn * 64 + j * 16 + lr;
        bpre_j[j] = bpre[n_j[j]];
        wv_j[j]   = wv[n_j[j]];
        wcov_j[j] = wcov[n_j[j]];
        tgt_j[j]  = target[n_j[j] * 64 + b];
    }
#pragma unroll
    for (int i = 0; i < 8; ++i) {
#pragma unroll
        for (int r = 0; r < 4; ++r) {
            int row_local = wm * 128 + i * 16 + quad * 4 + r;
            int m = m_base + row_local;
            int s = s_base + row_local;
            float c = cov[b * S_ + s];
            float esum = 0.f;
#pragma unroll
            for (int j = 0; j < 4; ++j) {
                float pre = acc[i][j][r] + bpre_j[j];
                __builtin_nontemporal_store(pre, &pre_out[(size_t)m * D_ + n_j[j]]);
                float t = fast_tanh(pre + tgt_j[j] + c * wcov_j[j]);
                esum += t * wv_j[j];
            }
            esum += __shfl_xor(esum, 1);
            esum += __shfl_xor(esum, 2);
            esum += __shfl_xor(esum, 4);
            esum += __shfl_xor(esum, 8);
            if (lr == 0) atomicAdd(&esm[row_local], esum);
        }
    }
    __syncthreads();
    epart[(size_t)(m_base + tid) * 8 + blockIdx.x] = esm[tid];
}

// ---------------- softmax over S + coverage_new ----------------
__global__ void softmax_cov_kernel(const float* __restrict__ epart, const float* __restrict__ cov,
                                   float* __restrict__ score, float* __restrict__ covnew) {
    int b = blockIdx.x, t = threadIdx.x;
    int lane = t & 63, wid = t >> 6;
    __shared__ float red[4];
    float e[4];
    float lmax = -3.4e38f;
#pragma unroll
    for (int p = 0; p < 4; ++p) {
        int s = p * 256 + t;
        const float4* q = reinterpret_cast<const float4*>(epart + (size_t)(b * S_ + s) * 8);
        float4 a = q[0], c = q[1];
        e[p] = a.x + a.y + a.z + a.w + c.x + c.y + c.z + c.w;
        lmax = fmaxf(lmax, e[p]);
    }
#pragma unroll
    for (int off = 1; off < 64; off <<= 1) lmax = fmaxf(lmax, __shfl_xor(lmax, off));
    if (lane == 0) red[wid] = lmax;
    __syncthreads();
    float bm = fmaxf(fmaxf(red[0], red[1]), fmaxf(red[2], red[3]));
    __syncthreads();
    float ex[4];
    float lsum = 0.f;
#pragma unroll
    for (int p = 0; p < 4; ++p) { ex[p] = __expf(e[p] - bm); lsum += ex[p]; }
#pragma unroll
    for (int off = 1; off < 64; off <<= 1) lsum += __shfl_xor(lsum, off);
    if (lane == 0) red[wid] = lsum;
    __syncthreads();
    float total = red[0] + red[1] + red[2] + red[3];
    float inv = __builtin_amdgcn_rcpf(total);
#pragma unroll
    for (int p = 0; p < 4; ++p) {
        int s = p * 256 + t;
        float sc = ex[p] * inv;
        score[b * S_ + s]  = sc;
        covnew[b * S_ + s] = cov[b * S_ + s] + sc;
    }
}

// ---------------- weightedContext = score @ context ----------------
__global__ void wc_partial_bf(const float* __restrict__ score, const u16* __restrict__ ctxb,
                              float* __restrict__ part) {
    int sp = blockIdx.x, b = blockIdx.y, t = threadIdx.x;   // sp in [0,16)
    int col = t * 4;
    float ax = 0.f, ay = 0.f, az = 0.f, aw = 0.f;
    const u16*   base  = ctxb + ((size_t)b * S_ + sp * 64) * K_ + col;
    const float* sbase = score + b * S_ + sp * 64;
    for (int ss = 0; ss < 64; ++ss) {
        float w = sbase[ss];
        u16x4 c = *reinterpret_cast<const u16x4*>(base + (size_t)ss * K_);
        ax += w * bf2f(c[0]); ay += w * bf2f(c[1]);
        az += w * bf2f(c[2]); aw += w * bf2f(c[3]);
    }
    float4 o = { ax, ay, az, aw };
    *reinterpret_cast<float4*>(part + (size_t)(b * 16 + sp) * 1024 + col) = o;
}

__global__ void wc_partial_f32(const float* __restrict__ score, const float* __restrict__ ctx,
                               float* __restrict__ part) {
    int sp = blockIdx.x, b = blockIdx.y, t = threadIdx.x;
    int col = t * 4;
    float ax = 0.f, ay = 0.f, az = 0.f, aw = 0.f;
    const float* base  = ctx + ((size_t)b * S_ + sp * 64) * K_ + col;
    const float* sbase = score + b * S_ + sp * 64;
    for (int ss = 0; ss < 64; ++ss) {
        float w = sbase[ss];
        float4 c = *reinterpret_cast<const float4*>(base + (size_t)ss * K_);
        ax += w * c.x; ay += w * c.y; az += w * c.z; aw += w * c.w;
    }
    float4 o = { ax, ay, az, aw };
    *reinterpret_cast<float4*>(part + (size_t)(b * 16 + sp) * 1024 + col) = o;
}

__global__ void wc_reduce_kernel(const float* __restrict__ part, float* __restrict__ wc) {
    int b = blockIdx.x, t = threadIdx.x;
    int col = t * 4;
    float ax = 0.f, ay = 0.f, az = 0.f, aw = 0.f;
#pragma unroll
    for (int p = 0; p < 16; ++p) {
        float4 v = *reinterpret_cast<const float4*>(part + (size_t)(b * 16 + p) * 1024 + col);
        ax += v.x; ay += v.y; az += v.z; aw += v.w;
    }
    float4 o = { ax, ay, az, aw };
    *reinterpret_cast<float4*>(wc + b * 1024 + col) = o;
}

// ---------------- host ----------------
extern "C" void kernel_launch(void* const* d_in, const int* in_sizes, int n_in,
                              void* d_out, int out_size, void* d_ws, size_t ws_size,
                              hipStream_t stream) {
    const float* input = (const float*)d_in[0];
    const float* ctx   = (const float*)d_in[1];
    const float* cov   = (const float*)d_in[2];
    const float* Wpre  = (const float*)d_in[3];
    const float* bpre  = (const float*)d_in[4];
    const float* Wq    = (const float*)d_in[5];
    const float* Wv    = (const float*)d_in[6];
    const float* Wcov  = (const float*)d_in[7];

    float* out        = (float*)d_out;
    float* out_wc     = out;                 // (B, 1024)
    float* out_score  = out + 65536;         // (B, S)
    float* out_covnew = out + 131072;        // (B, S)
    float* out_pre    = out + 196608;        // (B, S, D)

    char*  ws        = (char*)d_ws;
    float* ws_target = (float*)(ws + WS_TARGET);
    float* ws_epart  = (float*)(ws + WS_EPART);
    float* ws_wcpart = (float*)(ws + WS_WCPART);
    u16*   ws_wpre   = (u16*)(ws + WS_WPRE);
    u16*   ws_ctxbf  = (u16*)(ws + WS_CTXBF);

    const bool use_bf = (ws_size >= WS_NEED_BF);

    // 1. W_pre -> bf16
    convert_bf16x8_kernel<<<512, 256, 0, stream>>>(Wpre, ws_wpre);
    // 2. context -> bf16
    if (use_bf)
        convert_bf16x8_kernel<<<32768, 256, 0, stream>>>(ctx, ws_ctxbf);
    // 3. target = input @ W_q^T
    target_kernel<<<16384, 256, 0, stream>>>(input, Wq, ws_target);
    // 4. GEMM + fused tanh/energy epilogue (256x256 tiles: 256 mt x 4 nt)
    if (use_bf)
        gemm_ep_fast<<<1024, 512, 0, stream>>>(ws_ctxbf, ws_wpre, bpre, Wv, Wcov,
                                               ws_target, cov, out_pre, ws_epart);
    else {
        dim3 ggrid(8, 256);
        gemm_ep_fallback<<<ggrid, 256, 0, stream>>>(ctx, ws_wpre, bpre, Wv, Wcov,
                                                    ws_target, cov, out_pre, ws_epart);
    }
    // 5. softmax + coverage_new
    softmax_cov_kernel<<<64, 256, 0, stream>>>(ws_epart, cov, out_score, out_covnew);
    // 6. weightedContext
    if (use_bf)
        wc_partial_bf<<<dim3(16, 64), 256, 0, stream>>>(out_score, ws_ctxbf, ws_wcpart);
    else
        wc_partial_f32<<<dim3(16, 64), 256, 0, stream>>>(out_score, ctx, ws_wcpart);
    wc_reduce_kernel<<<64, 256, 0, stream>>>(ws_wcpart, out_wc);
}